// Round 5
// baseline (289.950 us; speedup 1.0000x reference)
//
#include <hip/hip_runtime.h>
#include <hip/hip_fp16.h>

// ---------------------------------------------------------------------------
// GCN (3 layers) + global mean pool + linear, fp32 in/out, MI355X.
// t'[i] = dinv[i] * h[i] W^T; h_next[i] = relu(dinv[i]*(t'[i]+sum t'[j]) + b)
// R3-R5: scattered 4B global stores/atomics = ~32B HBM sector each. Dense only.
// R9: fp16 t (128B row = 1 L2 line), absmax 1.2e-4.
// R13/R18/R20: agg+mm fusion fails if it cuts gather MLP or leaves W
//   unamortized per wave (R20: VGPR=28 -> serial W reloads, 113us).
// R21: 8-wide masked-parallel gather; aggfinal fuses agg3+pool+linear.
// R22: aggmm fusion (512thr/32 nodes, node per 16-lane group, lane owns 4
//   features, mm via LDS h + W-row regs). 58.7us, ~neutral vs split.
// R23: shfl-broadcast cs preload -> 48 "independent" gathers. 61us, FAILED:
//   VGPR=52 => compiler serialized loads into ~6-12-deep windows (48 in-flight
//   uint2 needs >=96 dest VGPRs). Latency-hop model right, window never built.
// R24 (this round): FORCE the window. Each 16-edge batch loads into an
//   explicitly unrolled uint2 ub[16] register array (static indexing -> regs),
//   sched_barrier(0), THEN mask-FMA consumption. 3 batches = ~4 latency hops
//   at 16-wide. Masked lanes clamp to one hot line (L1-hit). Same treatment
//   for aggfinal's 8-wide slice gather. Verify bit: VGPR must jump to ~100+.
// ---------------------------------------------------------------------------

#define CAPB 3072
#define BINTILE 4096

// fctr zero + per-graph inverse counts (binary search on sorted batch) +
// out seeded with bl (aggfinal accumulates atomically on top).
__global__ __launch_bounds__(256) void init_kernel(int* __restrict__ fctr,
                                                   const int* __restrict__ batch,
                                                   const float* __restrict__ bl,
                                                   float* __restrict__ invc,
                                                   float* __restrict__ out,
                                                   int n, int nb) {
    int t = blockIdx.x * blockDim.x + threadIdx.x;
    if (t < 512) fctr[t] = 0;
    if (t < nb) {
        int l = 0, r = n;
        while (l < r) { int m = (l + r) >> 1; if (batch[m] < t) l = m + 1; else r = m; }
        int lo = l;
        r = n;
        while (l < r) { int m = (l + r) >> 1; if (batch[m] < t + 1) l = m + 1; else r = m; }
        invc[t] = 1.0f / fmaxf((float)(l - lo), 1.0f);
#pragma unroll
        for (int o = 0; o < 16; ++o) out[t * 16 + o] = bl[o];
    }
}

// Bucket edges into 512 fine dst-ranges (fixed capacity CAPB, base=g*CAPB).
__global__ __launch_bounds__(256) void bin512_kernel(const int* __restrict__ src,
                                                     const int* __restrict__ dst,
                                                     int* __restrict__ fctr,
                                                     int2* __restrict__ recs2,
                                                     int e, int n) {
    __shared__ int lcnt[512], gbase[512];
    int tid = threadIdx.x;
    int s0  = blockIdx.x * BINTILE;
    lcnt[tid] = 0;
    lcnt[tid + 256] = 0;
    __syncthreads();
    int dv[16], bk[16];
#pragma unroll
    for (int k = 0; k < 16; ++k) {
        int i = s0 + tid + k * 256;  // coalesced
        if (i < e) {
            dv[k] = dst[i];
            bk[k] = (int)((512LL * dv[k]) / n);
            atomicAdd(&lcnt[bk[k]], 1);
        } else {
            bk[k] = -1;
        }
    }
    __syncthreads();
#pragma unroll
    for (int j = 0; j < 2; ++j) {
        int b = tid + j * 256;
        gbase[b] = b * CAPB + atomicAdd(&fctr[b], lcnt[b]);
        lcnt[b]  = 0;  // reuse as placement counter
    }
    __syncthreads();
#pragma unroll
    for (int k = 0; k < 16; ++k) {
        if (bk[k] >= 0) {
            int i = s0 + tid + k * 256;
            int p = gbase[bk[k]] + atomicAdd(&lcnt[bk[k]], 1);
            if (p < (bk[k] + 1) * CAPB) recs2[p] = make_int2(src[i], dv[k]);
        }
    }
}

// One block per fine bucket: LDS counting sort -> dense csr, rp/dinv, then
// fused mm1 for this bucket's nodes: t1 = fp16(dinv * x W1^T).
__global__ __launch_bounds__(256) void sortfill_mm_kernel(
    const int2* __restrict__ recs2, const int* __restrict__ fctr,
    int* __restrict__ rp, float* __restrict__ dinv, int* __restrict__ csr,
    const float* __restrict__ x, const float* __restrict__ W1,
    __half* __restrict__ t1, int n) {
    __shared__ int hist[128];
    __shared__ int lofs[129];
    __shared__ int stage[CAPB];
    __shared__ int redbuf[256];
    __shared__ float xrow[98 * 64];  // 25KB
    int g   = blockIdx.x;
    int N0  = (int)(((long long)n * g + 511) / 512);
    int N1  = (int)(((long long)n * (g + 1) + 511) / 512);
    int nn  = N1 - N0;  // <= 98
    int tid = threadIdx.x;
    int lane = tid & 63;
    int wave = tid >> 6;

    int partial = 0;
    for (int j = tid; j < g; j += 256) partial += min(fctr[j], CAPB);
    redbuf[tid] = partial;
    if (tid < 128) hist[tid] = 0;
    __syncthreads();
    for (int s = 128; s > 0; s >>= 1) {
        if (tid < s) redbuf[tid] += redbuf[tid + s];
        __syncthreads();
    }
    int base = redbuf[0];
    const int2* my = recs2 + (size_t)g * CAPB;
    int total = min(fctr[g], CAPB);
    for (int i = tid; i < total; i += 256)
        atomicAdd(&hist[my[i].y - N0], 1);
    __syncthreads();
    if (tid == 0) {
        int acc = 0;
        for (int k = 0; k < nn; ++k) { lofs[k] = acc; acc += hist[k]; }
        lofs[nn] = acc;
    }
    __syncthreads();
    if (tid < 128) hist[tid] = 0;  // placement counters
    __syncthreads();
    for (int i = tid; i < total; i += 256) {
        int2 rec = my[i];
        int  li  = rec.y - N0;
        int  pos = lofs[li] + atomicAdd(&hist[li], 1);
        stage[pos] = rec.x;  // pos < total <= CAPB
    }
    __syncthreads();
    for (int j = tid; j < total; j += 256) csr[base + j] = stage[j];
    if (tid < nn) {
        rp[N0 + tid]   = base + lofs[tid];
        int deg        = lofs[tid + 1] - lofs[tid];
        dinv[N0 + tid] = rsqrtf((float)(deg + 1));
    }
    if (g == 511 && tid == 0) rp[n] = base + total;

    // ---- fused mm1 for this bucket's nodes ----
    for (int idx = tid; idx < nn * 16; idx += 256)
        ((float4*)xrow)[idx] = ((const float4*)(x + (size_t)N0 * 64))[idx];
    float4 wreg[16];
    const float4* W4 = (const float4*)(W1 + lane * 64);
#pragma unroll
    for (int q = 0; q < 16; ++q) wreg[q] = W4[q];
    __syncthreads();
    for (int li = wave; li < nn; li += 4) {
        float dv = rsqrtf((float)(lofs[li + 1] - lofs[li] + 1));
        const float4* row = (const float4*)(xrow + li * 64);
        float acc = 0.0f;
#pragma unroll
        for (int q = 0; q < 16; ++q) {
            float4 hv = row[q];  // wave-uniform -> LDS broadcast
            acc += hv.x * wreg[q].x + hv.y * wreg[q].y +
                   hv.z * wreg[q].z + hv.w * wreg[q].w;
        }
        t1[(size_t)(N0 + li) * 64 + lane] = __float2half(acc * dv);
    }
}

// Fused agg(layer k) + mm(layer k+1): 512 thr = 8 waves, 32 nodes/block.
// GATHER (R24): per 16-edge batch, shfl-broadcast indices from the coalesced
// cs preload, issue ALL 16 uint2 loads into a static register array, THEN
// (after sched_barrier) convert+mask-FMA. 3 batches = ~4 wide latency hops.
// MM: proven mm_kernel body (W row/lane in 16 float4 regs, 4 rows/wave).
__global__ __launch_bounds__(512, 4) void aggmm_kernel(const __half* __restrict__ t,
                                                       const int* __restrict__ rp,
                                                       const int* __restrict__ cs,
                                                       const float* __restrict__ dinv,
                                                       const float* __restrict__ bias,
                                                       const float* __restrict__ W,
                                                       __half* __restrict__ tout, int n) {
    __shared__ float hs[32 * 64];  // 8KB
    __shared__ float dvs[32];
    int tid  = threadIdx.x;
    int lane = tid & 63;
    int wave = tid >> 6;        // 0..7
    int g    = lane >> 4;       // group = node slot 0..3
    int lb   = lane & 15;
    int fo   = lb << 2;         // lane owns features fo..fo+3
    int gs   = g << 4;
    int base = blockIdx.x * 32;
    int nl   = wave * 4 + g;    // local node 0..31
    int i    = base + nl;
    int ii   = min(i, n - 1);   // clamped for tail block; store guarded by i<n

    int beg  = rp[ii];
    int end  = rp[ii + 1];
    int deg  = end - beg;
    int last = max(end - 1, beg);  // deg==0 corner: stays in csr buffer

    // independent early loads: self row, norm, 48 edge indices
    uint2 su = *(const uint2*)(t + (size_t)ii * 64 + fo);
    float dv = dinv[ii];
    int c0 = cs[min(beg + lb,      last)];
    int c1 = cs[min(beg + 16 + lb, last)];
    int c2 = cs[min(beg + 32 + lb, last)];

    float4 a0 = make_float4(0.f, 0.f, 0.f, 0.f);
    float4 a1 = a0, a2 = a0, a3 = a0;

    // ---- batch 0: edges 0..15 ----
    {
        uint2 ub[16];
#pragma unroll
        for (int j = 0; j < 16; ++j) {
            int sj = __shfl(c0, gs + j, 64);       // = cs[beg_g + j]
            sj = min(max(sj, 0), n - 1);
            ub[j] = *(const uint2*)(t + (size_t)sj * 64 + fo);
        }
        __builtin_amdgcn_sched_barrier(0);
#pragma unroll
        for (int j = 0; j < 16; ++j) {
            float m  = (j < deg) ? 1.0f : 0.0f;
            float2 f0 = __half22float2(*(const __half2*)&ub[j].x);
            float2 f1 = __half22float2(*(const __half2*)&ub[j].y);
            float4& a = (j & 2) ? ((j & 1) ? a3 : a2) : ((j & 1) ? a1 : a0);
            a.x = fmaf(m, f0.x, a.x);
            a.y = fmaf(m, f0.y, a.y);
            a.z = fmaf(m, f1.x, a.z);
            a.w = fmaf(m, f1.y, a.w);
        }
    }
    // ---- batch 1: edges 16..31 ----
    {
        uint2 ub[16];
#pragma unroll
        for (int j = 0; j < 16; ++j) {
            int sj = __shfl(c1, gs + j, 64);       // = cs[beg_g + 16 + j]
            sj = min(max(sj, 0), n - 1);
            ub[j] = *(const uint2*)(t + (size_t)sj * 64 + fo);
        }
        __builtin_amdgcn_sched_barrier(0);
#pragma unroll
        for (int j = 0; j < 16; ++j) {
            float m  = (16 + j < deg) ? 1.0f : 0.0f;
            float2 f0 = __half22float2(*(const __half2*)&ub[j].x);
            float2 f1 = __half22float2(*(const __half2*)&ub[j].y);
            float4& a = (j & 2) ? ((j & 1) ? a3 : a2) : ((j & 1) ? a1 : a0);
            a.x = fmaf(m, f0.x, a.x);
            a.y = fmaf(m, f0.y, a.y);
            a.z = fmaf(m, f1.x, a.z);
            a.w = fmaf(m, f1.y, a.w);
        }
    }
    // ---- batch 2: edges 32..47 ----
    {
        uint2 ub[16];
#pragma unroll
        for (int j = 0; j < 16; ++j) {
            int sj = __shfl(c2, gs + j, 64);       // = cs[beg_g + 32 + j]
            sj = min(max(sj, 0), n - 1);
            ub[j] = *(const uint2*)(t + (size_t)sj * 64 + fo);
        }
        __builtin_amdgcn_sched_barrier(0);
#pragma unroll
        for (int j = 0; j < 16; ++j) {
            float m  = (32 + j < deg) ? 1.0f : 0.0f;
            float2 f0 = __half22float2(*(const __half2*)&ub[j].x);
            float2 f1 = __half22float2(*(const __half2*)&ub[j].y);
            float4& a = (j & 2) ? ((j & 1) ? a3 : a2) : ((j & 1) ? a1 : a0);
            a.x = fmaf(m, f0.x, a.x);
            a.y = fmaf(m, f0.y, a.y);
            a.z = fmaf(m, f1.x, a.z);
            a.w = fmaf(m, f1.y, a.w);
        }
    }
    // rare tail (deg > 48, ~1e-5 of nodes); bounds uniform within a group
    for (int b0 = beg + 48; b0 < end; b0 += 16) {
        int rc = cs[min(b0 + lb, end - 1)];
#pragma unroll
        for (int j = 0; j < 16; ++j) {
            int sj = __shfl(rc, gs + j, 64);
            sj = min(max(sj, 0), n - 1);
            uint2 u  = *(const uint2*)(t + (size_t)sj * 64 + fo);
            float m  = (b0 + j < end) ? 1.0f : 0.0f;
            float2 f0 = __half22float2(*(const __half2*)&u.x);
            float2 f1 = __half22float2(*(const __half2*)&u.y);
            float4& a = (j & 2) ? ((j & 1) ? a3 : a2) : ((j & 1) ? a1 : a0);
            a.x = fmaf(m, f0.x, a.x);
            a.y = fmaf(m, f0.y, a.y);
            a.z = fmaf(m, f1.x, a.z);
            a.w = fmaf(m, f1.y, a.w);
        }
    }

    if (i < n) {
        float2 s01 = __half22float2(*(const __half2*)&su.x);
        float2 s23 = __half22float2(*(const __half2*)&su.y);
        float4 bv = *(const float4*)(bias + fo);
        float4 h4;
        h4.x = fmaxf(fmaf(dv, ((a0.x + a1.x) + (a2.x + a3.x)) + s01.x, bv.x), 0.0f);
        h4.y = fmaxf(fmaf(dv, ((a0.y + a1.y) + (a2.y + a3.y)) + s01.y, bv.y), 0.0f);
        h4.z = fmaxf(fmaf(dv, ((a0.z + a1.z) + (a2.z + a3.z)) + s23.x, bv.z), 0.0f);
        h4.w = fmaxf(fmaf(dv, ((a0.w + a1.w) + (a2.w + a3.w)) + s23.y, bv.w), 0.0f);
        *(float4*)(hs + nl * 64 + fo) = h4;
        if (lb == 0) dvs[nl] = dv;
    }
    __syncthreads();

    // ---- mm phase (mm_kernel body, 4 rows/wave) ----
    float4 wreg[16];
    const float4* W4 = (const float4*)(W + lane * 64);
#pragma unroll
    for (int q = 0; q < 16; ++q) wreg[q] = W4[q];
#pragma unroll
    for (int rr = 0; rr < 4; ++rr) {
        int r  = wave * 4 + rr;
        int io = base + r;
        if (io < n) {
            const float4* row = (const float4*)(hs + r * 64);
            float acc = 0.0f;
#pragma unroll
            for (int q = 0; q < 16; ++q) {
                float4 hv = row[q];  // wave-uniform address -> LDS broadcast
                acc += hv.x * wreg[q].x + hv.y * wreg[q].y +
                       hv.z * wreg[q].z + hv.w * wreg[q].w;
            }
            tout[(size_t)io * 64 + lane] = __float2half(acc * dvs[r]);
        }
    }
}

// Final layer: slice gather (4 groups x deg/4), R24 batch-then-consume ->
// h3 on all lanes -> per-node z = h3 . Wl^T (chunk-aligned Wl frags),
// xor-reduce over chunks, 16 atomicAdds of z*inv_cnt into bl-seeded out.
__global__ __launch_bounds__(256, 6) void aggfinal_kernel(const __half* __restrict__ t,
                                                          const int* __restrict__ rp,
                                                          const int* __restrict__ cs,
                                                          const float* __restrict__ dinv,
                                                          const float* __restrict__ bias,
                                                          const float* __restrict__ Wl,
                                                          const int* __restrict__ batch,
                                                          const float* __restrict__ invc,
                                                          float* __restrict__ out, int n) {
    int gw   = (blockIdx.x * blockDim.x + threadIdx.x) >> 6;
    int lane = threadIdx.x & 63;
    if (gw >= n) return;
    int i   = gw;
    int grp = lane >> 4;
    int fo  = (lane & 15) << 2;
    int beg = rp[i];
    int end = rp[i + 1];
    uint2 su = *(const uint2*)(t + (size_t)i * 64 + fo);
    float dv = dinv[i];
    float4 bv = *(const float4*)(bias + fo);

    int deg = end - beg;
    int len = (deg + 3) >> 2;
    int gb  = beg + grp * len;
    int ge  = min(gb + len, end);

    float4 aa[4];
    aa[0] = make_float4(0.f, 0.f, 0.f, 0.f);
    aa[1] = aa[0]; aa[2] = aa[0]; aa[3] = aa[0];
    for (int eb = gb; eb < ge; eb += 8) {
        int sjv[8];
#pragma unroll
        for (int j = 0; j < 8; ++j) sjv[j] = cs[min(eb + j, end - 1)];
        uint2 ub[8];
#pragma unroll
        for (int j = 0; j < 8; ++j)
            ub[j] = *(const uint2*)(t + (size_t)sjv[j] * 64 + fo);
        __builtin_amdgcn_sched_barrier(0);
#pragma unroll
        for (int j = 0; j < 8; ++j) {
            float m  = (eb + j < ge) ? 1.0f : 0.0f;
            float2 f0 = __half22float2(*(const __half2*)&ub[j].x);
            float2 f1 = __half22float2(*(const __half2*)&ub[j].y);
            aa[j & 3].x = fmaf(m, f0.x, aa[j & 3].x);
            aa[j & 3].y = fmaf(m, f0.y, aa[j & 3].y);
            aa[j & 3].z = fmaf(m, f1.x, aa[j & 3].z);
            aa[j & 3].w = fmaf(m, f1.y, aa[j & 3].w);
        }
    }
    float4 acc;
    acc.x = (aa[0].x + aa[1].x) + (aa[2].x + aa[3].x);
    acc.y = (aa[0].y + aa[1].y) + (aa[2].y + aa[3].y);
    acc.z = (aa[0].z + aa[1].z) + (aa[2].z + aa[3].z);
    acc.w = (aa[0].w + aa[1].w) + (aa[2].w + aa[3].w);
    acc.x += __shfl_xor(acc.x, 16, 64);
    acc.y += __shfl_xor(acc.y, 16, 64);
    acc.z += __shfl_xor(acc.z, 16, 64);
    acc.w += __shfl_xor(acc.w, 16, 64);
    acc.x += __shfl_xor(acc.x, 32, 64);
    acc.y += __shfl_xor(acc.y, 32, 64);
    acc.z += __shfl_xor(acc.z, 32, 64);
    acc.w += __shfl_xor(acc.w, 32, 64);

    // all lanes hold h3[i][4*(lane&15) .. +3]
    float2 s01 = __half22float2(*(const __half2*)&su.x);
    float2 s23 = __half22float2(*(const __half2*)&su.y);
    float4 h4;
    h4.x = fmaxf(fmaf(dv, acc.x + s01.x, bv.x), 0.0f);
    h4.y = fmaxf(fmaf(dv, acc.y + s01.y, bv.y), 0.0f);
    h4.z = fmaxf(fmaf(dv, acc.z + s23.x, bv.z), 0.0f);
    h4.w = fmaxf(fmaf(dv, acc.w + s23.y, bv.w), 0.0f);

    // z[o] = h3 . Wl[o], o = 4m + grp; lane uses only its own chunk.
    float4 wl0 = *(const float4*)(Wl + (0 * 4 + grp) * 64 + fo);
    float4 wl1 = *(const float4*)(Wl + (1 * 4 + grp) * 64 + fo);
    float4 wl2 = *(const float4*)(Wl + (2 * 4 + grp) * 64 + fo);
    float4 wl3 = *(const float4*)(Wl + (3 * 4 + grp) * 64 + fo);
    float z0 = h4.x * wl0.x + h4.y * wl0.y + h4.z * wl0.z + h4.w * wl0.w;
    float z1 = h4.x * wl1.x + h4.y * wl1.y + h4.z * wl1.z + h4.w * wl1.w;
    float z2 = h4.x * wl2.x + h4.y * wl2.y + h4.z * wl2.z + h4.w * wl2.w;
    float z3 = h4.x * wl3.x + h4.y * wl3.y + h4.z * wl3.z + h4.w * wl3.w;
#pragma unroll
    for (int s = 1; s <= 8; s <<= 1) {
        z0 += __shfl_xor(z0, s, 64);
        z1 += __shfl_xor(z1, s, 64);
        z2 += __shfl_xor(z2, s, 64);
        z3 += __shfl_xor(z3, s, 64);
    }
    int m = lane & 15;
    if (m < 4) {
        int   b  = batch[i];
        float ic = invc[b];
        float zv = (m == 0) ? z0 : (m == 1) ? z1 : (m == 2) ? z2 : z3;
        atomicAdd(out + b * 16 + (m * 4 + grp), zv * ic);
    }
}

extern "C" void kernel_launch(void* const* d_in, const int* in_sizes, int n_in,
                              void* d_out, int out_size, void* d_ws, size_t ws_size,
                              hipStream_t stream) {
    const float* x    = (const float*)d_in[0];
    const int*   ei   = (const int*)d_in[1];
    const int*   batch= (const int*)d_in[2];
    const float* W1   = (const float*)d_in[3];
    const float* b1   = (const float*)d_in[4];
    const float* W2   = (const float*)d_in[5];
    const float* b2   = (const float*)d_in[6];
    const float* W3   = (const float*)d_in[7];
    const float* b3   = (const float*)d_in[8];
    const float* Wl   = (const float*)d_in[9];
    const float* bl   = (const float*)d_in[10];
    float* out = (float*)d_out;

    int n  = in_sizes[0] / 64;   // 50000 nodes
    int e  = in_sizes[1] / 2;    // 1250000 edges
    int nb = out_size / 16;      // 512 graphs

    const int* esrc = ei;
    const int* edst = ei + e;

    char* p = (char*)d_ws;
    auto carve = [&](size_t bytes) {
        char* r = p;
        p += (bytes + 255) & ~(size_t)255;
        return r;
    };
    float*  dinv  = (float*)carve((size_t)n * 4);
    int*    rp    = (int*)  carve((size_t)(n + 1) * 4);
    int*    csr   = (int*)  carve((size_t)e * 4);
    __half* tA    = (__half*)carve((size_t)n * 64 * 2);  // t1 / t3
    __half* tB    = (__half*)carve((size_t)n * 64 * 2);  // t2
    int2*   recs2 = (int2*) carve((size_t)512 * CAPB * 8);
    int*    fctr  = (int*)  carve(512 * 4);
    float*  invc  = (float*)carve((size_t)nb * 4);

    dim3 blk(256);
    int gBIN = (e + BINTILE - 1) / BINTILE;  // 306 tiles
    int gFUS = (n + 31) / 32;                // 32 nodes / 512-thr block
    int gAGG = (n + 3) / 4;                  // one node per wave (aggfinal)

    init_kernel<<<2, blk, 0, stream>>>(fctr, batch, bl, invc, out, n, nb);
    bin512_kernel<<<gBIN, blk, 0, stream>>>(esrc, edst, fctr, recs2, e, n);
    sortfill_mm_kernel<<<512, blk, 0, stream>>>(recs2, fctr, rp, dinv, csr,
                                                x, W1, tA, n);
    aggmm_kernel<<<gFUS, dim3(512), 0, stream>>>(tA, rp, csr, dinv, b1, W2, tB, n);
    aggmm_kernel<<<gFUS, dim3(512), 0, stream>>>(tB, rp, csr, dinv, b2, W3, tA, n);
    aggfinal_kernel<<<gAGG, blk, 0, stream>>>(tA, rp, csr, dinv, b3, Wl,
                                              batch, invc, out, n);
}